// Round 1
// baseline (1037.165 us; speedup 1.0000x reference)
//
#include <hip/hip_runtime.h>
#include <cstddef>
#include <cstdint>

#define LEAKY 0.2f
#define AGG_CAP 128   // edges staged per chunk in aggregate kernel

__device__ __forceinline__ float lrelu(float x) {
    return x > 0.f ? x : LEAKY * x;
}

// ---------------------------------------------------------------------------
// H[M,128] = A[M,128] @ W[128,128]   (fp32, W read via cache, A rows uniform)
// grid: (M+15)/16 blocks of 256 threads; thread = (rowgroup rg of 8 rows, col)
// ---------------------------------------------------------------------------
__global__ __launch_bounds__(256) void gemm128_k(const float* __restrict__ A,
                                                 const float* __restrict__ Wg,
                                                 float* __restrict__ H, int M)
{
    int row0 = blockIdx.x * 16;
    int col  = threadIdx.x & 127;
    int rg   = __builtin_amdgcn_readfirstlane(threadIdx.x >> 7);  // 0 or 1, wave-uniform

    float acc[8];
#pragma unroll
    for (int j = 0; j < 8; ++j) acc[j] = 0.f;

    for (int k = 0; k < 128; k += 4) {
        float w0 = Wg[(k + 0) * 128 + col];
        float w1 = Wg[(k + 1) * 128 + col];
        float w2 = Wg[(k + 2) * 128 + col];
        float w3 = Wg[(k + 3) * 128 + col];
#pragma unroll
        for (int j = 0; j < 8; ++j) {
            int r = row0 + rg * 8 + j;
            if (r >= M) r = M - 1;               // clamp (harmless redundant load)
            float4 xv = *(const float4*)(A + (size_t)r * 128 + k);
            acc[j] += xv.x * w0 + xv.y * w1 + xv.z * w2 + xv.w * w3;
        }
    }
#pragma unroll
    for (int j = 0; j < 8; ++j) {
        int r = row0 + rg * 8 + j;
        if (r < M) H[(size_t)r * 128 + col] = acc[j];
    }
}

// ---------------------------------------------------------------------------
// Per-node attention coefficients: asrc[n,h] = dot(h[n,h,:], a_src[h,:])
// grid: N blocks of 128 threads (thread = channel)
// ---------------------------------------------------------------------------
__global__ __launch_bounds__(128) void alphas_k(const float* __restrict__ h,
                                                const float* __restrict__ a_s,
                                                const float* __restrict__ a_d,
                                                float* __restrict__ asrc,
                                                float* __restrict__ adst, int N)
{
    int n = blockIdx.x;
    int t = threadIdx.x;
    int hd = t >> 5;
    float v = h[(size_t)n * 128 + t];
    float ps = v * a_s[t];
    float pd = v * a_d[t];
#pragma unroll
    for (int off = 16; off > 0; off >>= 1) {
        ps += __shfl_down(ps, off, 32);
        pd += __shfl_down(pd, off, 32);
    }
    if ((t & 31) == 0) {
        asrc[(size_t)n * 4 + hd] = ps;
        adst[(size_t)n * 4 + hd] = pd;
    }
}

// ---------------------------------------------------------------------------
// CSR build: histogram -> single-block scan -> fill
// ---------------------------------------------------------------------------
__global__ void hist_k(const int* __restrict__ dstv, int E, int* __restrict__ cnt)
{
    int e = blockIdx.x * blockDim.x + threadIdx.x;
    if (e < E) atomicAdd(&cnt[dstv[e]], 1);
}

__global__ __launch_bounds__(1024) void scan_k(const int* __restrict__ cnt,
                                               int* __restrict__ rowptr,
                                               int* __restrict__ cursor,
                                               int N, int Etot)
{
    __shared__ int wsum[16];
    __shared__ int chunk_tot;
    __shared__ int carry_s;
    int tid  = threadIdx.x;
    int lane = tid & 63;
    int wv   = tid >> 6;
    if (tid == 0) carry_s = 0;
    __syncthreads();
    for (int base = 0; base < N; base += 1024) {
        int i = base + tid;
        int v = (i < N) ? cnt[i] : 0;
        int x = v;
#pragma unroll
        for (int off = 1; off < 64; off <<= 1) {
            int y = __shfl_up(x, off, 64);
            if (lane >= off) x += y;
        }
        if (lane == 63) wsum[wv] = x;
        __syncthreads();
        if (wv == 0 && lane < 16) {
            int ws = wsum[lane];
            int xs = ws;
#pragma unroll
            for (int off = 1; off < 16; off <<= 1) {
                int y = __shfl_up(xs, off, 64);
                if (lane >= off) xs += y;
            }
            wsum[lane] = xs - ws;               // exclusive prefix of wave sums
            if (lane == 15) chunk_tot = xs;     // inclusive total of this chunk
        }
        __syncthreads();
        int excl = (x - v) + wsum[wv] + carry_s;
        if (i < N) { rowptr[i] = excl; cursor[i] = excl; }
        __syncthreads();
        if (tid == 0) carry_s += chunk_tot;
        __syncthreads();
    }
    if (tid == 0) rowptr[N] = Etot;
}

__global__ void fill_k(const int* __restrict__ srcv, const int* __restrict__ dstv,
                       int E, int* __restrict__ cursor, int* __restrict__ adj)
{
    int e = blockIdx.x * blockDim.x + threadIdx.x;
    if (e < E) {
        int d = dstv[e];
        int p = atomicAdd(&cursor[d], 1);
        adj[p] = srcv[e];
    }
}

// ---------------------------------------------------------------------------
// Per-destination-node softmax + aggregation (single pass, chunked online
// softmax). grid: N blocks of 128 threads (thread = output channel).
// Self-loop handled implicitly. final_flag: write out + per-head splits,
// else write elu(out) (layer-1 -> layer-2 input).
// ---------------------------------------------------------------------------
__global__ __launch_bounds__(128) void aggregate_k(
    const int* __restrict__ rowptr, const int* __restrict__ adj,
    const float* __restrict__ h, const float* __restrict__ asrc,
    const float* __restrict__ adst, const float* __restrict__ bias,
    float* __restrict__ out, int N, int final_flag)
{
    __shared__ int   s_idx[AGG_CAP];
    __shared__ float4 s_e[AGG_CAP];

    int n  = blockIdx.x;
    int t  = threadIdx.x;
    int hd = t >> 5;
    int beg = rowptr[n];
    int end = rowptr[n + 1];

    float4 ad4 = ((const float4*)adst)[n];
    float4 as4 = ((const float4*)asrc)[n];
    float es[4];
    es[0] = lrelu(as4.x + ad4.x);
    es[1] = lrelu(as4.y + ad4.y);
    es[2] = lrelu(as4.z + ad4.z);
    es[3] = lrelu(as4.w + ad4.w);
    float e_self = es[hd];

    // init online-softmax state with the self-loop edge
    float m    = e_self;
    float ssum = 1.0f;
    float acc  = h[(size_t)n * 128 + t];

    for (int cbeg = beg; cbeg < end; cbeg += AGG_CAP) {
        int cnt = end - cbeg;
        if (cnt > AGG_CAP) cnt = AGG_CAP;
        __syncthreads();
        if (t < cnt) {
            int s = adj[cbeg + t];
            s_idx[t] = s;
            float4 a4 = ((const float4*)asrc)[s];
            float4 e4;
            e4.x = lrelu(a4.x + ad4.x);
            e4.y = lrelu(a4.y + ad4.y);
            e4.z = lrelu(a4.z + ad4.z);
            e4.w = lrelu(a4.w + ad4.w);
            s_e[t] = e4;
        }
        __syncthreads();

        // chunk max for this head
        float cm = -1e30f;
        for (int j = 0; j < cnt; ++j)
            cm = fmaxf(cm, ((const float*)&s_e[j])[hd]);
        float mnew  = fmaxf(m, cm);
        float scale = __expf(m - mnew);
        ssum *= scale;
        acc  *= scale;
        m = mnew;

        for (int j = 0; j < cnt; ++j) {
            float ev = ((const float*)&s_e[j])[hd];
            float w  = __expf(ev - m);
            int   s  = s_idx[j];
            ssum += w;
            acc  += w * h[(size_t)s * 128 + t];
        }
    }

    float val = acc / (ssum + 1e-16f) + bias[t];
    if (final_flag) {
        out[(size_t)n * 128 + t] = val;
        int c = t & 31;
        out[(size_t)N * 128 + (size_t)hd * N * 32 + (size_t)n * 32 + c] = val;
    } else {
        out[(size_t)n * 128 + t] = val > 0.f ? val : expm1f(val);
    }
}

// ---------------------------------------------------------------------------
extern "C" void kernel_launch(void* const* d_in, const int* in_sizes, int n_in,
                              void* d_out, int out_size, void* d_ws, size_t ws_size,
                              hipStream_t stream)
{
    const float* x   = (const float*)d_in[0];
    const int*   ei  = (const int*)d_in[1];
    const float* W1  = (const float*)d_in[2];
    const float* aS1 = (const float*)d_in[3];
    const float* aD1 = (const float*)d_in[4];
    const float* b1  = (const float*)d_in[5];
    const float* W2  = (const float*)d_in[6];
    const float* aS2 = (const float*)d_in[7];
    const float* aD2 = (const float*)d_in[8];
    const float* b2  = (const float*)d_in[9];
    float* out = (float*)d_out;

    int N = in_sizes[0] / 128;
    int E = in_sizes[1] / 2;
    const int* srcv = ei;
    const int* dstv = ei + E;

    char* p = (char*)d_ws;
    auto alloc = [&](size_t bytes) {
        char* r = p;
        p += (bytes + 255) & ~(size_t)255;
        return r;
    };
    float* h      = (float*)alloc((size_t)N * 128 * 4);
    float* x2     = (float*)alloc((size_t)N * 128 * 4);
    float* asrc   = (float*)alloc((size_t)N * 4 * 4);
    float* adst   = (float*)alloc((size_t)N * 4 * 4);
    int*   cnt    = (int*)alloc((size_t)N * 4);
    int*   rowptr = (int*)alloc((size_t)(N + 1) * 4);
    int*   cursor = (int*)alloc((size_t)N * 4);
    int*   adj    = (int*)alloc((size_t)E * 4);

    // ---- CSR build (shared by both layers) ----
    hipMemsetAsync(cnt, 0, (size_t)N * 4, stream);
    hist_k<<<(E + 255) / 256, 256, 0, stream>>>(dstv, E, cnt);
    scan_k<<<1, 1024, 0, stream>>>(cnt, rowptr, cursor, N, E);
    fill_k<<<(E + 255) / 256, 256, 0, stream>>>(srcv, dstv, E, cursor, adj);

    int gemm_grid = (N + 15) / 16;

    // ---- layer 1 ----
    gemm128_k<<<gemm_grid, 256, 0, stream>>>(x, W1, h, N);
    alphas_k<<<N, 128, 0, stream>>>(h, aS1, aD1, asrc, adst, N);
    aggregate_k<<<N, 128, 0, stream>>>(rowptr, adj, h, asrc, adst, b1, x2, N, 0);

    // ---- layer 2 ----
    gemm128_k<<<gemm_grid, 256, 0, stream>>>(x2, W2, h, N);
    alphas_k<<<N, 128, 0, stream>>>(h, aS2, aD2, asrc, adst, N);
    aggregate_k<<<N, 128, 0, stream>>>(rowptr, adj, h, asrc, adst, b2, out, N, 1);
}

// Round 2
// 911.901 us; speedup vs baseline: 1.1374x; 1.1374x over previous
//
#include <hip/hip_runtime.h>
#include <cstddef>
#include <cstdint>

#define LEAKY 0.2f
#define AGG_CAP 128   // edges staged per chunk in aggregate kernel

__device__ __forceinline__ float lrelu(float x) {
    return x > 0.f ? x : LEAKY * x;
}

// ---------------------------------------------------------------------------
// H[M,128] = A[M,128] @ W[128,128]  (fp32)
// Block = 256 threads -> 64-row x 128-col output tile.
// K=128 total: stage the whole 64x128 A-tile in LDS once (stride 129 pad),
// then full-K accumulation. lane = row (LDS reads conflict-free), column
// group is wave-uniform so W loads go down the scalar path:
// inner op is v_fmac acc[j], s_w[j], v_a  -> FMA-bound.
// ---------------------------------------------------------------------------
#define GROWS 64
__global__ __launch_bounds__(256) void gemm128_k(const float* __restrict__ A,
                                                 const float* __restrict__ Wg,
                                                 float* __restrict__ H, int M)
{
    __shared__ float As[GROWS][129];
    int t  = threadIdx.x;
    int r0 = blockIdx.x * GROWS;

    // ---- stage A tile: 64 rows x 128 k = 2048 float4, 8 per thread ----
#pragma unroll
    for (int i = 0; i < 8; ++i) {
        int f   = t + i * 256;        // float4 index within tile
        int row = f >> 5;             // 32 float4 per row
        int k4  = (f & 31) * 4;
        int gr  = r0 + row;
        if (gr >= M) gr = M - 1;      // clamp (redundant load, harmless)
        float4 v = *(const float4*)(A + (size_t)gr * 128 + k4);
        As[row][k4 + 0] = v.x;
        As[row][k4 + 1] = v.y;
        As[row][k4 + 2] = v.z;
        As[row][k4 + 3] = v.w;
    }
    __syncthreads();

    int row = t & 63;                                          // per-lane
    int cg  = __builtin_amdgcn_readfirstlane(t >> 6);          // wave-uniform 0..3
    const float* __restrict__ wbase = Wg + cg * 32;

    float acc[32];
#pragma unroll
    for (int j = 0; j < 32; ++j) acc[j] = 0.f;

#pragma unroll 2
    for (int k = 0; k < 128; ++k) {
        float a = As[row][k];                  // broadcast-free LDS read
        const float* __restrict__ wr = wbase + k * 128;        // scalar addr
#pragma unroll
        for (int j = 0; j < 32; ++j)
            acc[j] += a * wr[j];
    }

    int gr = r0 + row;
    if (gr < M) {
        float4* o = (float4*)(H + (size_t)gr * 128 + cg * 32);
#pragma unroll
        for (int j8 = 0; j8 < 8; ++j8)
            o[j8] = make_float4(acc[4 * j8], acc[4 * j8 + 1],
                                acc[4 * j8 + 2], acc[4 * j8 + 3]);
    }
}

// ---------------------------------------------------------------------------
// Per-node attention coefficients: asrc[n,h] = dot(h[n,h,:], a_src[h,:])
// grid: N blocks of 128 threads (thread = channel)
// ---------------------------------------------------------------------------
__global__ __launch_bounds__(128) void alphas_k(const float* __restrict__ h,
                                                const float* __restrict__ a_s,
                                                const float* __restrict__ a_d,
                                                float* __restrict__ asrc,
                                                float* __restrict__ adst, int N)
{
    int n = blockIdx.x;
    int t = threadIdx.x;
    int hd = t >> 5;
    float v = h[(size_t)n * 128 + t];
    float ps = v * a_s[t];
    float pd = v * a_d[t];
#pragma unroll
    for (int off = 16; off > 0; off >>= 1) {
        ps += __shfl_down(ps, off, 32);
        pd += __shfl_down(pd, off, 32);
    }
    if ((t & 31) == 0) {
        asrc[(size_t)n * 4 + hd] = ps;
        adst[(size_t)n * 4 + hd] = pd;
    }
}

// ---------------------------------------------------------------------------
// CSR build: histogram -> single-block scan -> fill
// ---------------------------------------------------------------------------
__global__ void hist_k(const int* __restrict__ dstv, int E, int* __restrict__ cnt)
{
    int e = blockIdx.x * blockDim.x + threadIdx.x;
    if (e < E) atomicAdd(&cnt[dstv[e]], 1);
}

__global__ __launch_bounds__(1024) void scan_k(const int* __restrict__ cnt,
                                               int* __restrict__ rowptr,
                                               int* __restrict__ cursor,
                                               int N, int Etot)
{
    __shared__ int wsum[16];
    __shared__ int chunk_tot;
    __shared__ int carry_s;
    int tid  = threadIdx.x;
    int lane = tid & 63;
    int wv   = tid >> 6;
    if (tid == 0) carry_s = 0;
    __syncthreads();
    for (int base = 0; base < N; base += 1024) {
        int i = base + tid;
        int v = (i < N) ? cnt[i] : 0;
        int x = v;
#pragma unroll
        for (int off = 1; off < 64; off <<= 1) {
            int y = __shfl_up(x, off, 64);
            if (lane >= off) x += y;
        }
        if (lane == 63) wsum[wv] = x;
        __syncthreads();
        if (wv == 0 && lane < 16) {
            int ws = wsum[lane];
            int xs = ws;
#pragma unroll
            for (int off = 1; off < 16; off <<= 1) {
                int y = __shfl_up(xs, off, 64);
                if (lane >= off) xs += y;
            }
            wsum[lane] = xs - ws;               // exclusive prefix of wave sums
            if (lane == 15) chunk_tot = xs;     // inclusive total of this chunk
        }
        __syncthreads();
        int excl = (x - v) + wsum[wv] + carry_s;
        if (i < N) { rowptr[i] = excl; cursor[i] = excl; }
        __syncthreads();
        if (tid == 0) carry_s += chunk_tot;
        __syncthreads();
    }
    if (tid == 0) rowptr[N] = Etot;
}

__global__ void fill_k(const int* __restrict__ srcv, const int* __restrict__ dstv,
                       int E, int* __restrict__ cursor, int* __restrict__ adj)
{
    int e = blockIdx.x * blockDim.x + threadIdx.x;
    if (e < E) {
        int d = dstv[e];
        int p = atomicAdd(&cursor[d], 1);
        adj[p] = srcv[e];
    }
}

// ---------------------------------------------------------------------------
// Per-destination-node softmax + aggregation (single pass, chunked online
// softmax). grid: N blocks of 128 threads (thread = output channel).
// Self-loop handled implicitly. final_flag: write out + per-head splits,
// else write elu(out) (layer-1 -> layer-2 input).
// ---------------------------------------------------------------------------
__global__ __launch_bounds__(128) void aggregate_k(
    const int* __restrict__ rowptr, const int* __restrict__ adj,
    const float* __restrict__ h, const float* __restrict__ asrc,
    const float* __restrict__ adst, const float* __restrict__ bias,
    float* __restrict__ out, int N, int final_flag)
{
    __shared__ int   s_idx[AGG_CAP];
    __shared__ float4 s_e[AGG_CAP];

    int n  = blockIdx.x;
    int t  = threadIdx.x;
    int hd = t >> 5;
    int beg = rowptr[n];
    int end = rowptr[n + 1];

    float4 ad4 = ((const float4*)adst)[n];
    float4 as4 = ((const float4*)asrc)[n];
    float es[4];
    es[0] = lrelu(as4.x + ad4.x);
    es[1] = lrelu(as4.y + ad4.y);
    es[2] = lrelu(as4.z + ad4.z);
    es[3] = lrelu(as4.w + ad4.w);
    float e_self = es[hd];

    // init online-softmax state with the self-loop edge
    float m    = e_self;
    float ssum = 1.0f;
    float acc  = h[(size_t)n * 128 + t];

    for (int cbeg = beg; cbeg < end; cbeg += AGG_CAP) {
        int cnt = end - cbeg;
        if (cnt > AGG_CAP) cnt = AGG_CAP;
        __syncthreads();
        if (t < cnt) {
            int s = adj[cbeg + t];
            s_idx[t] = s;
            float4 a4 = ((const float4*)asrc)[s];
            float4 e4;
            e4.x = lrelu(a4.x + ad4.x);
            e4.y = lrelu(a4.y + ad4.y);
            e4.z = lrelu(a4.z + ad4.z);
            e4.w = lrelu(a4.w + ad4.w);
            s_e[t] = e4;
        }
        __syncthreads();

        // chunk max for this head
        float cm = -1e30f;
        for (int j = 0; j < cnt; ++j)
            cm = fmaxf(cm, ((const float*)&s_e[j])[hd]);
        float mnew  = fmaxf(m, cm);
        float scale = __expf(m - mnew);
        ssum *= scale;
        acc  *= scale;
        m = mnew;

        for (int j = 0; j < cnt; ++j) {
            float ev = ((const float*)&s_e[j])[hd];
            float w  = __expf(ev - m);
            int   s  = s_idx[j];
            ssum += w;
            acc  += w * h[(size_t)s * 128 + t];
        }
    }

    float val = acc / (ssum + 1e-16f) + bias[t];
    if (final_flag) {
        out[(size_t)n * 128 + t] = val;
        int c = t & 31;
        out[(size_t)N * 128 + (size_t)hd * N * 32 + (size_t)n * 32 + c] = val;
    } else {
        out[(size_t)n * 128 + t] = val > 0.f ? val : expm1f(val);
    }
}

// ---------------------------------------------------------------------------
extern "C" void kernel_launch(void* const* d_in, const int* in_sizes, int n_in,
                              void* d_out, int out_size, void* d_ws, size_t ws_size,
                              hipStream_t stream)
{
    const float* x   = (const float*)d_in[0];
    const int*   ei  = (const int*)d_in[1];
    const float* W1  = (const float*)d_in[2];
    const float* aS1 = (const float*)d_in[3];
    const float* aD1 = (const float*)d_in[4];
    const float* b1  = (const float*)d_in[5];
    const float* W2  = (const float*)d_in[6];
    const float* aS2 = (const float*)d_in[7];
    const float* aD2 = (const float*)d_in[8];
    const float* b2  = (const float*)d_in[9];
    float* out = (float*)d_out;

    int N = in_sizes[0] / 128;
    int E = in_sizes[1] / 2;
    const int* srcv = ei;
    const int* dstv = ei + E;

    char* p = (char*)d_ws;
    auto alloc = [&](size_t bytes) {
        char* r = p;
        p += (bytes + 255) & ~(size_t)255;
        return r;
    };
    float* h      = (float*)alloc((size_t)N * 128 * 4);
    float* x2     = (float*)alloc((size_t)N * 128 * 4);
    float* asrc   = (float*)alloc((size_t)N * 4 * 4);
    float* adst   = (float*)alloc((size_t)N * 4 * 4);
    int*   cnt    = (int*)alloc((size_t)N * 4);
    int*   rowptr = (int*)alloc((size_t)(N + 1) * 4);
    int*   cursor = (int*)alloc((size_t)N * 4);
    int*   adj    = (int*)alloc((size_t)E * 4);

    // ---- CSR build (shared by both layers) ----
    hipMemsetAsync(cnt, 0, (size_t)N * 4, stream);
    hist_k<<<(E + 255) / 256, 256, 0, stream>>>(dstv, E, cnt);
    scan_k<<<1, 1024, 0, stream>>>(cnt, rowptr, cursor, N, E);
    fill_k<<<(E + 255) / 256, 256, 0, stream>>>(srcv, dstv, E, cursor, adj);

    int gemm_grid = (N + GROWS - 1) / GROWS;

    // ---- layer 1 ----
    gemm128_k<<<gemm_grid, 256, 0, stream>>>(x, W1, h, N);
    alphas_k<<<N, 128, 0, stream>>>(h, aS1, aD1, asrc, adst, N);
    aggregate_k<<<N, 128, 0, stream>>>(rowptr, adj, h, asrc, adst, b1, x2, N, 0);

    // ---- layer 2 ----
    gemm128_k<<<gemm_grid, 256, 0, stream>>>(x2, W2, h, N);
    alphas_k<<<N, 128, 0, stream>>>(h, aS2, aD2, asrc, adst, N);
    aggregate_k<<<N, 128, 0, stream>>>(rowptr, adj, h, asrc, adst, b2, out, N, 1);
}

// Round 3
// 873.587 us; speedup vs baseline: 1.1872x; 1.0439x over previous
//
#include <hip/hip_runtime.h>
#include <cstddef>
#include <cstdint>

#define LEAKY 0.2f
#define AGG_CAP 128   // edges staged per chunk in aggregate kernel

__device__ __forceinline__ float lrelu(float x) {
    return x > 0.f ? x : LEAKY * x;
}

// ---------------------------------------------------------------------------
// H[M,128] = A[M,128] @ W[128,128]  (fp32), fused per-node attention alphas.
// Block = 256 threads -> 64-row x 128-col output tile.
// K=128 total: stage the whole 64x128 A-tile in LDS once (stride 129 pad),
// then full-K accumulation. lane = row (LDS reads conflict-free), column
// group cg is wave-uniform so W loads go down the scalar path.
// Epilogue: thread (row, cg) holds exactly head cg's 32 channels of its row,
// so asrc/adst are a local 32-FMA dot + one store each (alphas_k fused away).
// ---------------------------------------------------------------------------
#define GROWS 64
__global__ __launch_bounds__(256) void gemm128_k(const float* __restrict__ A,
                                                 const float* __restrict__ Wg,
                                                 const float* __restrict__ a_s,
                                                 const float* __restrict__ a_d,
                                                 float* __restrict__ H,
                                                 float* __restrict__ asrc,
                                                 float* __restrict__ adst, int M)
{
    __shared__ float As[GROWS][129];
    int t  = threadIdx.x;
    int r0 = blockIdx.x * GROWS;

    // ---- stage A tile: 64 rows x 128 k = 2048 float4, 8 per thread ----
#pragma unroll
    for (int i = 0; i < 8; ++i) {
        int f   = t + i * 256;        // float4 index within tile
        int row = f >> 5;             // 32 float4 per row
        int k4  = (f & 31) * 4;
        int gr  = r0 + row;
        if (gr >= M) gr = M - 1;      // clamp (redundant load, harmless)
        float4 v = *(const float4*)(A + (size_t)gr * 128 + k4);
        As[row][k4 + 0] = v.x;
        As[row][k4 + 1] = v.y;
        As[row][k4 + 2] = v.z;
        As[row][k4 + 3] = v.w;
    }
    __syncthreads();

    int row = t & 63;                                          // per-lane
    int cg  = __builtin_amdgcn_readfirstlane(t >> 6);          // wave-uniform 0..3
    const float* __restrict__ wbase = Wg + cg * 32;

    float acc[32];
#pragma unroll
    for (int j = 0; j < 32; ++j) acc[j] = 0.f;

#pragma unroll 2
    for (int k = 0; k < 128; ++k) {
        float a = As[row][k];                  // conflict-free LDS read
        const float* __restrict__ wr = wbase + k * 128;        // scalar addr
#pragma unroll
        for (int j = 0; j < 32; ++j)
            acc[j] += a * wr[j];
    }

    int gr = r0 + row;
    if (gr < M) {
        float4* o = (float4*)(H + (size_t)gr * 128 + cg * 32);
#pragma unroll
        for (int j8 = 0; j8 < 8; ++j8)
            o[j8] = make_float4(acc[4 * j8], acc[4 * j8 + 1],
                                acc[4 * j8 + 2], acc[4 * j8 + 3]);
        // fused alphas: head cg channels are exactly acc[0..31]
        float ps = 0.f, pd = 0.f;
#pragma unroll
        for (int j = 0; j < 32; ++j) {
            ps += acc[j] * a_s[cg * 32 + j];   // scalar (wave-uniform) loads
            pd += acc[j] * a_d[cg * 32 + j];
        }
        asrc[(size_t)gr * 4 + cg] = ps;
        adst[(size_t)gr * 4 + cg] = pd;
    }
}

// ---------------------------------------------------------------------------
// CSR build: histogram -> single-block scan -> fill
// ---------------------------------------------------------------------------
__global__ void hist_k(const int* __restrict__ dstv, int E, int* __restrict__ cnt)
{
    int e = blockIdx.x * blockDim.x + threadIdx.x;
    if (e < E) atomicAdd(&cnt[dstv[e]], 1);
}

__global__ __launch_bounds__(1024) void scan_k(const int* __restrict__ cnt,
                                               int* __restrict__ rowptr,
                                               int* __restrict__ cursor,
                                               int N, int Etot)
{
    __shared__ int wsum[16];
    __shared__ int chunk_tot;
    __shared__ int carry_s;
    int tid  = threadIdx.x;
    int lane = tid & 63;
    int wv   = tid >> 6;
    if (tid == 0) carry_s = 0;
    __syncthreads();
    for (int base = 0; base < N; base += 1024) {
        int i = base + tid;
        int v = (i < N) ? cnt[i] : 0;
        int x = v;
#pragma unroll
        for (int off = 1; off < 64; off <<= 1) {
            int y = __shfl_up(x, off, 64);
            if (lane >= off) x += y;
        }
        if (lane == 63) wsum[wv] = x;
        __syncthreads();
        if (wv == 0 && lane < 16) {
            int ws = wsum[lane];
            int xs = ws;
#pragma unroll
            for (int off = 1; off < 16; off <<= 1) {
                int y = __shfl_up(xs, off, 64);
                if (lane >= off) xs += y;
            }
            wsum[lane] = xs - ws;               // exclusive prefix of wave sums
            if (lane == 15) chunk_tot = xs;     // inclusive total of this chunk
        }
        __syncthreads();
        int excl = (x - v) + wsum[wv] + carry_s;
        if (i < N) { rowptr[i] = excl; cursor[i] = excl; }
        __syncthreads();
        if (tid == 0) carry_s += chunk_tot;
        __syncthreads();
    }
    if (tid == 0) rowptr[N] = Etot;
}

__global__ void fill_k(const int* __restrict__ srcv, const int* __restrict__ dstv,
                       int E, int* __restrict__ cursor, int* __restrict__ adj)
{
    int e = blockIdx.x * blockDim.x + threadIdx.x;
    if (e < E) {
        int d = dstv[e];
        int p = atomicAdd(&cursor[d], 1);
        adj[p] = srcv[e];
    }
}

// ---------------------------------------------------------------------------
// Per-destination-node softmax + aggregation, restructured:
// per-head scalar work (max / exp / weight-sum) done once per edge by the
// 32 lanes of each head group (strided + shfl reduce) instead of 32x
// redundantly; main per-edge loop is 2 broadcast LDS reads + 32-bit voffset
// add + global gather + fmac. grid: N blocks of 128 threads.
// ---------------------------------------------------------------------------
__global__ __launch_bounds__(128) void aggregate_k(
    const int* __restrict__ rowptr, const int* __restrict__ adj,
    const float* __restrict__ h, const float* __restrict__ asrc,
    const float* __restrict__ adst, const float* __restrict__ bias,
    float* __restrict__ out, int N, int final_flag)
{
    __shared__ float    s_w[4][AGG_CAP];   // e, then w=exp(e-m), per head
    __shared__ unsigned s_off[AGG_CAP];    // src byte offsets (s << 9)

    int n  = blockIdx.x;
    int t  = threadIdx.x;
    int hd = t >> 5;
    int l  = t & 31;
    int beg = rowptr[n];
    int end = rowptr[n + 1];

    float4 ad4 = ((const float4*)adst)[n];
    float4 as4 = ((const float4*)asrc)[n];
    float e_self = lrelu(((const float*)&as4)[hd] + ((const float*)&ad4)[hd]);

    // online-softmax state, seeded with the self-loop edge
    float m    = e_self;
    float ssum = 1.0f;
    unsigned t4 = (unsigned)t * 4u;
    const char* __restrict__ hb = (const char*)h;
    float acc  = h[(size_t)n * 128 + t];

    for (int cbeg = beg; cbeg < end; cbeg += AGG_CAP) {
        int cnt = end - cbeg;
        if (cnt > AGG_CAP) cnt = AGG_CAP;
        __syncthreads();
        if (t < cnt) {
            int s = adj[cbeg + t];
            s_off[t] = (unsigned)s << 9;
            float4 a4 = ((const float4*)asrc)[s];
            s_w[0][t] = lrelu(a4.x + ad4.x);
            s_w[1][t] = lrelu(a4.y + ad4.y);
            s_w[2][t] = lrelu(a4.z + ad4.z);
            s_w[3][t] = lrelu(a4.w + ad4.w);
        }
        __syncthreads();

        // chunk max for this head (strided over the head group's 32 lanes)
        float cm = -1e30f;
        for (int j = l; j < cnt; j += 32)
            cm = fmaxf(cm, s_w[hd][j]);
#pragma unroll
        for (int mk = 16; mk > 0; mk >>= 1)
            cm = fmaxf(cm, __shfl_xor(cm, mk, 32));

        float mnew  = fmaxf(m, cm);
        float scale = __expf(m - mnew);
        ssum *= scale;
        acc  *= scale;
        m = mnew;

        // w = exp(e - m) in place, plus chunk weight-sum
        float ws = 0.f;
        for (int j = l; j < cnt; j += 32) {
            float w = __expf(s_w[hd][j] - m);
            s_w[hd][j] = w;
            ws += w;
        }
#pragma unroll
        for (int mk = 16; mk > 0; mk >>= 1)
            ws += __shfl_xor(ws, mk, 32);
        ssum += ws;
        __syncthreads();

        // weighted gather: per edge = 2 broadcast LDS reads + add + load + fmac
#pragma unroll 4
        for (int j = 0; j < cnt; ++j) {
            float w = s_w[hd][j];
            unsigned off = s_off[j] + t4;
            acc = fmaf(w, *(const float*)(hb + off), acc);
        }
    }

    float val = acc / (ssum + 1e-16f) + bias[t];
    if (final_flag) {
        out[(size_t)n * 128 + t] = val;
        int c = t & 31;
        out[(size_t)N * 128 + (size_t)hd * N * 32 + (size_t)n * 32 + c] = val;
    } else {
        out[(size_t)n * 128 + t] = val > 0.f ? val : expm1f(val);
    }
}

// ---------------------------------------------------------------------------
extern "C" void kernel_launch(void* const* d_in, const int* in_sizes, int n_in,
                              void* d_out, int out_size, void* d_ws, size_t ws_size,
                              hipStream_t stream)
{
    const float* x   = (const float*)d_in[0];
    const int*   ei  = (const int*)d_in[1];
    const float* W1  = (const float*)d_in[2];
    const float* aS1 = (const float*)d_in[3];
    const float* aD1 = (const float*)d_in[4];
    const float* b1  = (const float*)d_in[5];
    const float* W2  = (const float*)d_in[6];
    const float* aS2 = (const float*)d_in[7];
    const float* aD2 = (const float*)d_in[8];
    const float* b2  = (const float*)d_in[9];
    float* out = (float*)d_out;

    int N = in_sizes[0] / 128;
    int E = in_sizes[1] / 2;
    const int* srcv = ei;
    const int* dstv = ei + E;

    char* p = (char*)d_ws;
    auto alloc = [&](size_t bytes) {
        char* r = p;
        p += (bytes + 255) & ~(size_t)255;
        return r;
    };
    float* h      = (float*)alloc((size_t)N * 128 * 4);
    float* x2     = (float*)alloc((size_t)N * 128 * 4);
    float* asrc   = (float*)alloc((size_t)N * 4 * 4);
    float* adst   = (float*)alloc((size_t)N * 4 * 4);
    int*   cnt    = (int*)alloc((size_t)N * 4);
    int*   rowptr = (int*)alloc((size_t)(N + 1) * 4);
    int*   cursor = (int*)alloc((size_t)N * 4);
    int*   adj    = (int*)alloc((size_t)E * 4);

    // ---- CSR build (shared by both layers) ----
    hipMemsetAsync(cnt, 0, (size_t)N * 4, stream);
    hist_k<<<(E + 255) / 256, 256, 0, stream>>>(dstv, E, cnt);
    scan_k<<<1, 1024, 0, stream>>>(cnt, rowptr, cursor, N, E);
    fill_k<<<(E + 255) / 256, 256, 0, stream>>>(srcv, dstv, E, cursor, adj);

    int gemm_grid = (N + GROWS - 1) / GROWS;

    // ---- layer 1 ----
    gemm128_k<<<gemm_grid, 256, 0, stream>>>(x, W1, aS1, aD1, h, asrc, adst, N);
    aggregate_k<<<N, 128, 0, stream>>>(rowptr, adj, h, asrc, adst, b1, x2, N, 0);

    // ---- layer 2 ----
    gemm128_k<<<gemm_grid, 256, 0, stream>>>(x2, W2, aS2, aD2, h, asrc, adst, N);
    aggregate_k<<<N, 128, 0, stream>>>(rowptr, adj, h, asrc, adst, b2, out, N, 1);
}

// Round 4
// 702.197 us; speedup vs baseline: 1.4770x; 1.2441x over previous
//
#include <hip/hip_runtime.h>
#include <hip/hip_fp16.h>
#include <cstddef>
#include <cstdint>

#define LEAKY 0.2f
#define AGG_CAP 128   // edges staged per chunk in aggregate kernel

__device__ __forceinline__ float lrelu(float x) {
    return x > 0.f ? x : LEAKY * x;
}

// ---------------------------------------------------------------------------
// H[M,128] = A[M,128] @ W[128,128]  (fp32 accum), fused per-node alphas.
// Block = 256 threads -> 64-row x 128-col output tile; K=128 staged once in
// LDS (stride-129 pad). lane = row, column group cg wave-uniform (scalar W
// loads). Epilogue: H stored as FP16 (gather consumer halves its traffic);
// alphas (head cg = acc[0..31]) computed in fp32 and stored.
// ---------------------------------------------------------------------------
#define GROWS 64
__global__ __launch_bounds__(256) void gemm128_k(const float* __restrict__ A,
                                                 const float* __restrict__ Wg,
                                                 const float* __restrict__ a_s,
                                                 const float* __restrict__ a_d,
                                                 __half* __restrict__ H,
                                                 float* __restrict__ asrc,
                                                 float* __restrict__ adst, int M)
{
    __shared__ float As[GROWS][129];
    int t  = threadIdx.x;
    int r0 = blockIdx.x * GROWS;

    // ---- stage A tile: 64 rows x 128 k = 2048 float4, 8 per thread ----
#pragma unroll
    for (int i = 0; i < 8; ++i) {
        int f   = t + i * 256;        // float4 index within tile
        int row = f >> 5;             // 32 float4 per row
        int k4  = (f & 31) * 4;
        int gr  = r0 + row;
        if (gr >= M) gr = M - 1;      // clamp (redundant load, harmless)
        float4 v = *(const float4*)(A + (size_t)gr * 128 + k4);
        As[row][k4 + 0] = v.x;
        As[row][k4 + 1] = v.y;
        As[row][k4 + 2] = v.z;
        As[row][k4 + 3] = v.w;
    }
    __syncthreads();

    int row = t & 63;                                          // per-lane
    int cg  = __builtin_amdgcn_readfirstlane(t >> 6);          // wave-uniform 0..3
    const float* __restrict__ wbase = Wg + cg * 32;

    float acc[32];
#pragma unroll
    for (int j = 0; j < 32; ++j) acc[j] = 0.f;

#pragma unroll 2
    for (int k = 0; k < 128; ++k) {
        float a = As[row][k];                  // conflict-free LDS read
        const float* __restrict__ wr = wbase + k * 128;        // scalar addr
#pragma unroll
        for (int j = 0; j < 32; ++j)
            acc[j] += a * wr[j];
    }

    int gr = r0 + row;
    if (gr < M) {
        __half hv[32];
#pragma unroll
        for (int j = 0; j < 32; ++j) hv[j] = __float2half(acc[j]);
        float4* o = (float4*)((char*)H + (size_t)gr * 256 + cg * 64);
#pragma unroll
        for (int j4 = 0; j4 < 4; ++j4)
            o[j4] = ((const float4*)hv)[j4];

        // fused alphas: head cg channels are exactly acc[0..31] (fp32)
        float ps = 0.f, pd = 0.f;
#pragma unroll
        for (int j = 0; j < 32; ++j) {
            ps += acc[j] * a_s[cg * 32 + j];   // scalar (wave-uniform) loads
            pd += acc[j] * a_d[cg * 32 + j];
        }
        asrc[(size_t)gr * 4 + cg] = ps;
        adst[(size_t)gr * 4 + cg] = pd;
    }
}

// ---------------------------------------------------------------------------
// CSR build: histogram -> hierarchical scan (3 small kernels) -> fill
// ---------------------------------------------------------------------------
__global__ void hist_k(const int* __restrict__ dstv, int E, int* __restrict__ cnt)
{
    int e = blockIdx.x * blockDim.x + threadIdx.x;
    if (e < E) atomicAdd(&cnt[dstv[e]], 1);
}

// per-256-chunk sums
__global__ __launch_bounds__(256) void psum_k(const int* __restrict__ cnt,
                                              int* __restrict__ bsum, int N)
{
    __shared__ int ws[4];
    int i = blockIdx.x * 256 + threadIdx.x;
    int v = (i < N) ? cnt[i] : 0;
    int lane = threadIdx.x & 63, wv = threadIdx.x >> 6;
#pragma unroll
    for (int off = 32; off > 0; off >>= 1)
        v += __shfl_xor(v, off, 64);
    if (lane == 0) ws[wv] = v;
    __syncthreads();
    if (threadIdx.x == 0)
        bsum[blockIdx.x] = ws[0] + ws[1] + ws[2] + ws[3];
}

// exclusive scan of the (<=512) chunk sums, single tiny block
__global__ __launch_bounds__(512) void scanb_k(int* __restrict__ bsum,
                                               int* __restrict__ bbase,
                                               int NB, int* __restrict__ rowptr,
                                               int N, int Etot)
{
    __shared__ int wsum[8];
    int tid = threadIdx.x;
    int lane = tid & 63, wv = tid >> 6;
    int v = (tid < NB) ? bsum[tid] : 0;
    int x = v;
#pragma unroll
    for (int off = 1; off < 64; off <<= 1) {
        int y = __shfl_up(x, off, 64);
        if (lane >= off) x += y;
    }
    if (lane == 63) wsum[wv] = x;
    __syncthreads();
    if (tid == 0) {
        int run = 0;
#pragma unroll
        for (int w = 0; w < 8; ++w) { int s = wsum[w]; wsum[w] = run; run += s; }
        rowptr[N] = Etot;
    }
    __syncthreads();
    if (tid < NB) bbase[tid] = (x - v) + wsum[wv];
}

// per-chunk exclusive scan + add chunk base -> rowptr & cursor
__global__ __launch_bounds__(256) void scatter_k(const int* __restrict__ cnt,
                                                 const int* __restrict__ bbase,
                                                 int* __restrict__ rowptr,
                                                 int* __restrict__ cursor, int N)
{
    __shared__ int wsum[4];
    int i = blockIdx.x * 256 + threadIdx.x;
    int v = (i < N) ? cnt[i] : 0;
    int lane = threadIdx.x & 63, wv = threadIdx.x >> 6;
    int x = v;
#pragma unroll
    for (int off = 1; off < 64; off <<= 1) {
        int y = __shfl_up(x, off, 64);
        if (lane >= off) x += y;
    }
    if (lane == 63) wsum[wv] = x;
    __syncthreads();
    if (threadIdx.x == 0) {
        int run = 0;
#pragma unroll
        for (int w = 0; w < 4; ++w) { int s = wsum[w]; wsum[w] = run; run += s; }
    }
    __syncthreads();
    int excl = (x - v) + wsum[wv] + bbase[blockIdx.x];
    if (i < N) { rowptr[i] = excl; cursor[i] = excl; }
}

__global__ void fill_k(const int* __restrict__ srcv, const int* __restrict__ dstv,
                       int E, int* __restrict__ cursor, int* __restrict__ adj)
{
    int e = blockIdx.x * blockDim.x + threadIdx.x;
    if (e < E) {
        int d = dstv[e];
        int p = atomicAdd(&cursor[d], 1);
        adj[p] = srcv[e];
    }
}

// ---------------------------------------------------------------------------
// Per-destination-node softmax + aggregation. Per-head scalar work done once
// per edge by each head group's 32 lanes; main per-edge loop is 2 broadcast
// LDS reads + 32-bit voffset add + fp16 global gather + fmac.
// grid: N blocks of 128 threads.
// ---------------------------------------------------------------------------
__global__ __launch_bounds__(128) void aggregate_k(
    const int* __restrict__ rowptr, const int* __restrict__ adj,
    const __half* __restrict__ h, const float* __restrict__ asrc,
    const float* __restrict__ adst, const float* __restrict__ bias,
    float* __restrict__ out, int N, int final_flag)
{
    __shared__ float    s_w[4][AGG_CAP];   // e, then w=exp(e-m), per head
    __shared__ unsigned s_off[AGG_CAP];    // src byte offsets (s << 8, fp16 rows)

    int n  = blockIdx.x;
    int t  = threadIdx.x;
    int hd = t >> 5;
    int l  = t & 31;
    int beg = rowptr[n];
    int end = rowptr[n + 1];

    float4 ad4 = ((const float4*)adst)[n];
    float4 as4 = ((const float4*)asrc)[n];
    float e_self = lrelu(((const float*)&as4)[hd] + ((const float*)&ad4)[hd]);

    // online-softmax state, seeded with the self-loop edge
    float m    = e_self;
    float ssum = 1.0f;
    unsigned t2 = (unsigned)t * 2u;
    const char* __restrict__ hb = (const char*)h;
    float acc  = __half2float(h[(size_t)n * 128 + t]);

    for (int cbeg = beg; cbeg < end; cbeg += AGG_CAP) {
        int cnt = end - cbeg;
        if (cnt > AGG_CAP) cnt = AGG_CAP;
        __syncthreads();
        if (t < cnt) {
            int s = adj[cbeg + t];
            s_off[t] = (unsigned)s << 8;
            float4 a4 = ((const float4*)asrc)[s];
            s_w[0][t] = lrelu(a4.x + ad4.x);
            s_w[1][t] = lrelu(a4.y + ad4.y);
            s_w[2][t] = lrelu(a4.z + ad4.z);
            s_w[3][t] = lrelu(a4.w + ad4.w);
        }
        __syncthreads();

        // chunk max for this head (strided over the head group's 32 lanes)
        float cm = -1e30f;
        for (int j = l; j < cnt; j += 32)
            cm = fmaxf(cm, s_w[hd][j]);
#pragma unroll
        for (int mk = 16; mk > 0; mk >>= 1)
            cm = fmaxf(cm, __shfl_xor(cm, mk, 32));

        float mnew  = fmaxf(m, cm);
        float scale = __expf(m - mnew);
        ssum *= scale;
        acc  *= scale;
        m = mnew;

        // w = exp(e - m) in place, plus chunk weight-sum
        float ws = 0.f;
        for (int j = l; j < cnt; j += 32) {
            float w = __expf(s_w[hd][j] - m);
            s_w[hd][j] = w;
            ws += w;
        }
#pragma unroll
        for (int mk = 16; mk > 0; mk >>= 1)
            ws += __shfl_xor(ws, mk, 32);
        ssum += ws;
        __syncthreads();

        // weighted gather: per edge = 2 broadcast LDS reads + add + fp16 load + fmac
#pragma unroll 4
        for (int j = 0; j < cnt; ++j) {
            float w = s_w[hd][j];
            unsigned off = s_off[j] + t2;
            acc = fmaf(w, __half2float(*(const __half*)(hb + off)), acc);
        }
    }

    float val = acc / (ssum + 1e-16f) + bias[t];
    if (final_flag) {
        out[(size_t)n * 128 + t] = val;
        int c = t & 31;
        out[(size_t)N * 128 + (size_t)hd * N * 32 + (size_t)n * 32 + c] = val;
    } else {
        out[(size_t)n * 128 + t] = val > 0.f ? val : expm1f(val);
    }
}

// ---------------------------------------------------------------------------
extern "C" void kernel_launch(void* const* d_in, const int* in_sizes, int n_in,
                              void* d_out, int out_size, void* d_ws, size_t ws_size,
                              hipStream_t stream)
{
    const float* x   = (const float*)d_in[0];
    const int*   ei  = (const int*)d_in[1];
    const float* W1  = (const float*)d_in[2];
    const float* aS1 = (const float*)d_in[3];
    const float* aD1 = (const float*)d_in[4];
    const float* b1  = (const float*)d_in[5];
    const float* W2  = (const float*)d_in[6];
    const float* aS2 = (const float*)d_in[7];
    const float* aD2 = (const float*)d_in[8];
    const float* b2  = (const float*)d_in[9];
    float* out = (float*)d_out;

    int N = in_sizes[0] / 128;
    int E = in_sizes[1] / 2;
    const int* srcv = ei;
    const int* dstv = ei + E;

    char* p = (char*)d_ws;
    auto alloc = [&](size_t bytes) {
        char* r = p;
        p += (bytes + 255) & ~(size_t)255;
        return r;
    };
    __half* h    = (__half*)alloc((size_t)N * 128 * 2);
    float* x2     = (float*)alloc((size_t)N * 128 * 4);
    float* asrc   = (float*)alloc((size_t)N * 4 * 4);
    float* adst   = (float*)alloc((size_t)N * 4 * 4);
    int*   cnt    = (int*)alloc((size_t)N * 4);
    int*   rowptr = (int*)alloc((size_t)(N + 1) * 4);
    int*   cursor = (int*)alloc((size_t)N * 4);
    int*   adj    = (int*)alloc((size_t)E * 4);
    int NB = (N + 255) / 256;
    int*   bsum   = (int*)alloc((size_t)NB * 4);
    int*   bbase  = (int*)alloc((size_t)NB * 4);

    // ---- CSR build (shared by both layers) ----
    hipMemsetAsync(cnt, 0, (size_t)N * 4, stream);
    hist_k<<<(E + 255) / 256, 256, 0, stream>>>(dstv, E, cnt);
    psum_k<<<NB, 256, 0, stream>>>(cnt, bsum, N);
    scanb_k<<<1, 512, 0, stream>>>(bsum, bbase, NB, rowptr, N, E);
    scatter_k<<<NB, 256, 0, stream>>>(cnt, bbase, rowptr, cursor, N);
    fill_k<<<(E + 255) / 256, 256, 0, stream>>>(srcv, dstv, E, cursor, adj);

    int gemm_grid = (N + GROWS - 1) / GROWS;

    // ---- layer 1 ----
    gemm128_k<<<gemm_grid, 256, 0, stream>>>(x, W1, aS1, aD1, h, asrc, adst, N);
    aggregate_k<<<N, 128, 0, stream>>>(rowptr, adj, h, asrc, adst, b1, x2, N, 0);

    // ---- layer 2 ----
    gemm128_k<<<gemm_grid, 256, 0, stream>>>(x2, W2, aS2, aD2, h, asrc, adst, N);
    aggregate_k<<<N, 128, 0, stream>>>(rowptr, adj, h, asrc, adst, b2, out, N, 1);
}